// Round 1
// baseline (190.826 us; speedup 1.0000x reference)
//
#include <hip/hip_runtime.h>

#define BATCH 1024
#define DIN   4096
#define DOUT  4096
#define BB    128
#define KIN   32
#define KOUT  32
#define NF    65   // BB/2 + 1
#define TWOPI_OVER_B 0.049087385212340517f  // 2*pi/128

// workspace layout (floats):
//   tw  : 128 float2                     off 0       (256 floats)
//   wfs : [KOUT][NF][KIN] float2         off 256     (133120 floats)
//   X   : [BATCH][NF][KIN] float2        off 133376  (4259840 floats)
//   Y   : [BATCH][KOUT][NF] float2       next        (4259840 floats)
// total 34,612,224 bytes

__global__ __launch_bounds__(128) void k_init_tw(float2* __restrict__ tw) {
    int m = threadIdx.x;
    float ang = TWOPI_OVER_B * (float)m;
    float s, c;
    sincosf(ang, &s, &c);
    tw[m] = make_float2(c, s);
}

// wfs[o][k][j] = conj(FFT(W[o][j][:]))[k] * w_k / 128, w_k = 1 for k=0,64 else 2
__global__ __launch_bounds__(256) void k_init_wfs(const float* __restrict__ W,
                                                  float2* __restrict__ wfs) {
    int i = blockIdx.x * 256 + threadIdx.x;   // i = (o*NF + k)*KIN + j
    if (i >= KOUT * NF * KIN) return;
    int j  = i & 31;
    int ok = i >> 5;
    int k  = ok % NF;
    int o  = ok / NF;
    const float* w = W + (size_t)(o * KIN + j) * BB;
    float re = 0.f, im = 0.f;
    int m = 0;
    for (int s = 0; s < BB; ++s) {
        float ang = TWOPI_OVER_B * (float)m;
        float sn, cs;
        sincosf(ang, &sn, &cs);
        float wv = w[s];
        re = fmaf(wv, cs, re);
        im = fmaf(wv, sn, im);         // conj => e^{+i theta}
        m = (m + k) & 127;
    }
    float scale = (k == 0 || k == 64) ? (1.0f / 128.0f) : (2.0f / 128.0f);
    wfs[i] = make_float2(re * scale, im * scale);
}

// X[n][k][j] = sum_t xd[n, j*128+t] * e^{-2pi i k t / 128},  k = 0..64
// block: one n, 8 k's x 32 j's; x row (times D) staged in LDS.
// Lane j starts its t-walk at t=j (rotation) -> conflict-free LDS reads.
__global__ __launch_bounds__(256) void k_fdft(const float* __restrict__ x,
                                              const float* __restrict__ D,
                                              const float2* __restrict__ tw,
                                              float2* __restrict__ X) {
    __shared__ float  xs[DIN];
    __shared__ float2 twl[BB];
    int tid = threadIdx.x;
    int n  = blockIdx.x / 9;
    int kt = blockIdx.x % 9;
    if (tid < BB) twl[tid] = tw[tid];
    {
        const float4* xr  = (const float4*)(x + (size_t)n * DIN);
        const float4* Dr  = (const float4*)D;
        float4*       xsv = (float4*)xs;
        for (int f = tid; f < DIN / 4; f += 256) {
            float4 a = xr[f], d = Dr[f];
            xsv[f] = make_float4(a.x * d.x, a.y * d.y, a.z * d.z, a.w * d.w);
        }
    }
    __syncthreads();
    int j = tid & 31;
    int k = kt * 8 + (tid >> 5);
    if (k >= NF) return;
    const float* xrow = xs + j * BB;
    float re = 0.f, im = 0.f;
    int tp = j;                 // t' = (it + j) & 127
    int m  = (k * j) & 127;     // m = (k * t') & 127
    #pragma unroll 4
    for (int it = 0; it < BB; ++it) {
        float  v  = xrow[tp];
        float2 cs = twl[m];
        re = fmaf(v,  cs.x, re);
        im = fmaf(-v, cs.y, im);
        tp = (tp + 1) & 127;
        m  = (m + k) & 127;
    }
    X[((size_t)n * NF + k) * KIN + j] = make_float2(re, im);
}

// Y[n][o][k] = sum_j X[n][k][j] * wfs[o][k][j]   (complex), 2 n's per block.
// X staged in LDS with additive swizzle [k*32 + ((j+k)&31)] -> conflict-free.
__global__ __launch_bounds__(256) void k_einsum(const float2* __restrict__ X,
                                                const float2* __restrict__ wfs,
                                                float2* __restrict__ Y) {
    __shared__ float2 Xs[2][NF * KIN];
    int tid = threadIdx.x;
    int n0  = blockIdx.x * 2;
    for (int f = tid; f < 2 * NF * KIN; f += 256) {
        int nn = (f >= NF * KIN) ? 1 : 0;
        int r  = f - nn * NF * KIN;
        int k  = r >> 5, j = r & 31;
        Xs[nn][(k << 5) + ((j + k) & 31)] = X[(size_t)(n0 + nn) * NF * KIN + r];
    }
    __syncthreads();
    for (int oki = tid; oki < KOUT * NF; oki += 256) {
        int o = oki / NF;
        int k = oki - o * NF;
        const float2* wrow = wfs + (size_t)oki * KIN;
        const float2* x0 = &Xs[0][k << 5];
        const float2* x1 = &Xs[1][k << 5];
        float r0 = 0.f, i0 = 0.f, r1 = 0.f, i1 = 0.f;
        int jr = k & 31;
        #pragma unroll 8
        for (int j = 0; j < KIN; ++j) {
            float2 wv = wrow[j];
            float2 a  = x0[jr];
            float2 b  = x1[jr];
            r0 = fmaf(a.x, wv.x, r0); r0 = fmaf(-a.y, wv.y, r0);
            i0 = fmaf(a.x, wv.y, i0); i0 = fmaf( a.y, wv.x, i0);
            r1 = fmaf(b.x, wv.x, r1); r1 = fmaf(-b.y, wv.y, r1);
            i1 = fmaf(b.x, wv.y, i1); i1 = fmaf( b.y, wv.x, i1);
            jr = (jr + 1) & 31;
        }
        Y[(size_t)(n0 + 0) * KOUT * NF + oki] = make_float2(r0, i0);
        Y[(size_t)(n0 + 1) * KOUT * NF + oki] = make_float2(r1, i1);
    }
}

// out[n, o*128+t] = sum_{k=0}^{64} (Yr[k] cos(2pi k t/128) - Yi[k] sin(2pi k t/128))
// (weights w_k/128 already folded into wfs). Block: one n, 2 o's x 128 t's.
__global__ __launch_bounds__(256) void k_idft(const float2* __restrict__ Y,
                                              const float2* __restrict__ tw,
                                              float* __restrict__ out) {
    __shared__ float2 twl[BB];
    __shared__ float2 Ys[2 * NF];
    int tid = threadIdx.x;
    int n  = blockIdx.x >> 4;
    int ot = blockIdx.x & 15;
    if (tid < BB) twl[tid] = tw[tid];
    int o0 = ot * 2;
    for (int f = tid; f < 2 * NF; f += 256) {
        Ys[f] = Y[((size_t)n * KOUT + o0) * NF + f];
    }
    __syncthreads();
    int oo = tid >> 7;
    int t  = tid & 127;
    const float2* yrow = Ys + oo * NF;
    float acc = 0.f;
    int m = 0;                  // m = (k * t) & 127
    #pragma unroll 5
    for (int k = 0; k < NF; ++k) {
        float2 yv = yrow[k];
        float2 cs = twl[m];
        acc = fmaf(yv.x,  cs.x, acc);
        acc = fmaf(-yv.y, cs.y, acc);
        m = (m + t) & 127;
    }
    out[(size_t)n * DOUT + (o0 + oo) * BB + t] = acc;
}

extern "C" void kernel_launch(void* const* d_in, const int* in_sizes, int n_in,
                              void* d_out, int out_size, void* d_ws, size_t ws_size,
                              hipStream_t stream) {
    const float* x = (const float*)d_in[0];
    const float* W = (const float*)d_in[1];
    const float* D = (const float*)d_in[2];
    float* out = (float*)d_out;
    float* ws  = (float*)d_ws;

    float2* tw  = (float2*)ws;                            // 128
    float2* wfs = (float2*)(ws + 256);                    // 66560
    float2* X   = (float2*)(ws + 256 + 133120);           // 2129920
    float2* Y   = X + (size_t)BATCH * NF * KIN;           // 2129920

    k_init_tw <<<1, 128, 0, stream>>>(tw);
    k_init_wfs<<<(KOUT * NF * KIN + 255) / 256, 256, 0, stream>>>(W, wfs);
    k_fdft    <<<BATCH * 9, 256, 0, stream>>>(x, D, tw, X);
    k_einsum  <<<BATCH / 2, 256, 0, stream>>>(X, wfs, Y);
    k_idft    <<<BATCH * 16, 256, 0, stream>>>(Y, tw, out);
}

// Round 2
// 78.230 us; speedup vs baseline: 2.4393x; 2.4393x over previous
//
#include <hip/hip_runtime.h>
#include <hip/hip_bf16.h>

#define BATCH 1024
#define NF    65
#define TWOPI_OVER_B 0.049087385212340517f  // 2*pi/128

typedef __attribute__((ext_vector_type(8))) short bf16x8;
typedef __attribute__((ext_vector_type(4))) float f32x4;

static __device__ __forceinline__ unsigned short f2bf(float f) {
    __hip_bfloat16 h = __float2bfloat16(f);
    return *reinterpret_cast<unsigned short*>(&h);
}

// ---------------------------------------------------------------------------
// DFT matrices in MFMA B-fragment order (bf16), built once per launch.
// fragB : stage-A B-operand, B[t][kr] = Cmat[kr][t], 9 col-tiles x 4 k-blocks
//         Cmat[kr][t] = cos(2pi kr t/128)          kr in [0,65)
//                     = -sin(2pi (kr-65) t/128)    kr in [65,130), else 0
// fragCi: stage-C B-operand, Ci[kr][t] (K=160 padded, N=128), 8 ct x 5 kb
__global__ __launch_bounds__(256) void k_init_frag(unsigned short* __restrict__ fragB,
                                                   unsigned short* __restrict__ fragCi) {
    int i = blockIdx.x * 256 + threadIdx.x;
    if (i < 18432) {                       // fragB: ((c*4+kb)*64 + l)*8 + e
        int e = i & 7, l = (i >> 3) & 63, kb = (i >> 9) & 3, c = i >> 11;
        int kr = c * 16 + (l & 15);
        int t  = kb * 32 + (l >> 4) * 8 + e;
        float v = 0.f;
        if (kr < 65)       v =  cosf(TWOPI_OVER_B * (float)((kr * t) & 127));
        else if (kr < 130) v = -sinf(TWOPI_OVER_B * (float)(((kr - 65) * t) & 127));
        fragB[i] = f2bf(v);
    }
    if (i < 20480) {                       // fragCi: ((c*5+kb)*64 + l)*8 + e
        int e = i & 7, l = (i >> 3) & 63;
        int ckb = i >> 9; int kb = ckb % 5, c = ckb / 5;
        int kr = kb * 32 + (l >> 4) * 8 + e;
        int t  = c * 16 + (l & 15);
        float v = 0.f;
        if (kr < 65)       v =  cosf(TWOPI_OVER_B * (float)((kr * t) & 127));
        else if (kr < 130) v = -sinf(TWOPI_OVER_B * (float)(((kr - 65) * t) & 127));
        fragCi[i] = f2bf(v);
    }
}

// ---------------------------------------------------------------------------
// Shared MFMA DFT body: 64 rows (A, bf16 in swizzled LDS) x [128x130] Cmat.
// A-frag: lane l holds A[l&15][(l>>4)*8+e]; B read from fragment-ordered global.
// Result goes to LDS f32 [64][145] (145: coprime-32 stride, conflict-free).
#define SMEM_A_BYTES 37120   // max(xs 16384, Yl 64*145*4=37120)

// Stage A: X[n][k][j] = DFT_k(xd[n, j*128 + :])
__global__ __launch_bounds__(256) void k_fdft_mfma(const float* __restrict__ x,
                                                   const float* __restrict__ D,
                                                   const bf16x8* __restrict__ fragB,
                                                   float2* __restrict__ X) {
    __shared__ char smem[SMEM_A_BYTES];
    unsigned long long* xs8 = (unsigned long long*)smem;
    float* Yl = (float*)smem;
    int tid = threadIdx.x;
    int n0 = blockIdx.x * 2;

    #pragma unroll
    for (int it = 0; it < 8; ++it) {       // 2048 float4 = 2 rows of x
        int f  = tid + it * 256;
        int nn = f >> 10;
        int f4 = f & 1023;
        float4 xa = ((const float4*)(x + (size_t)(n0 + nn) * 4096))[f4];
        float4 da = ((const float4*)D)[f4];
        int rl = nn * 32 + (f4 >> 5);
        int t0 = (f4 & 31) * 4;
        unsigned long long pk =
              (unsigned long long)f2bf(xa.x * da.x)
            | ((unsigned long long)f2bf(xa.y * da.y) << 16)
            | ((unsigned long long)f2bf(xa.z * da.z) << 32)
            | ((unsigned long long)f2bf(xa.w * da.w) << 48);
        int byte = (rl * 256 + t0 * 2) ^ ((rl & 7) << 4);
        xs8[byte >> 3] = pk;
    }
    __syncthreads();

    int l = tid & 63, w = tid >> 6;
    int rl_a = w * 16 + (l & 15);
    int coff = (l >> 4) * 16;
    bf16x8 a[4];
    #pragma unroll
    for (int kb = 0; kb < 4; ++kb) {
        int byte = (rl_a * 256 + kb * 64 + coff) ^ ((rl_a & 7) << 4);
        a[kb] = *(const bf16x8*)(smem + byte);
    }
    f32x4 acc[9];
    #pragma unroll
    for (int c = 0; c < 9; ++c) acc[c] = (f32x4)0.f;
    #pragma unroll
    for (int c = 0; c < 9; ++c)
        #pragma unroll
        for (int kb = 0; kb < 4; ++kb)
            acc[c] = __builtin_amdgcn_mfma_f32_16x16x32_bf16(a[kb], fragB[(c * 4 + kb) * 64 + l], acc[c], 0, 0, 0);
    __syncthreads();                        // xs dead; reuse as Yl

    int rowd = w * 16 + (l >> 4) * 4;
    int cold = l & 15;
    #pragma unroll
    for (int c = 0; c < 9; ++c)
        #pragma unroll
        for (int r = 0; r < 4; ++r)
            Yl[(rowd + r) * 145 + c * 16 + cold] = acc[c][r];
    __syncthreads();

    for (int c2 = tid; c2 < 4160; c2 += 256) {
        int nn = (c2 >= 2080) ? 1 : 0;
        int r  = c2 - nn * 2080;
        int k  = r >> 5, j = r & 31;
        int rl = nn * 32 + j;
        X[(size_t)(n0 + nn) * 2080 + r] =
            make_float2(Yl[rl * 145 + k], Yl[rl * 145 + 65 + k]);
    }
}

// W spectrum: wfs[o][k][j] = conj(FFT(W[o][j][:]))[k] * w_k/128 — same GEMM.
__global__ __launch_bounds__(256) void k_wfs_mfma(const float* __restrict__ W,
                                                  const bf16x8* __restrict__ fragB,
                                                  float2* __restrict__ wfs) {
    __shared__ char smem[SMEM_A_BYTES];
    unsigned long long* xs8 = (unsigned long long*)smem;
    float* Yl = (float*)smem;
    int tid = threadIdx.x;
    int o0 = blockIdx.x * 2;

    #pragma unroll
    for (int it = 0; it < 8; ++it) {        // 64 rows x 128 = 2048 float4, contiguous
        int f  = tid + it * 256;
        float4 wa = ((const float4*)W)[(size_t)blockIdx.x * 2048 + f];
        int rl = f >> 5;
        int t0 = (f & 31) * 4;
        unsigned long long pk =
              (unsigned long long)f2bf(wa.x)
            | ((unsigned long long)f2bf(wa.y) << 16)
            | ((unsigned long long)f2bf(wa.z) << 32)
            | ((unsigned long long)f2bf(wa.w) << 48);
        int byte = (rl * 256 + t0 * 2) ^ ((rl & 7) << 4);
        xs8[byte >> 3] = pk;
    }
    __syncthreads();

    int l = tid & 63, w = tid >> 6;
    int rl_a = w * 16 + (l & 15);
    int coff = (l >> 4) * 16;
    bf16x8 a[4];
    #pragma unroll
    for (int kb = 0; kb < 4; ++kb) {
        int byte = (rl_a * 256 + kb * 64 + coff) ^ ((rl_a & 7) << 4);
        a[kb] = *(const bf16x8*)(smem + byte);
    }
    f32x4 acc[9];
    #pragma unroll
    for (int c = 0; c < 9; ++c) acc[c] = (f32x4)0.f;
    #pragma unroll
    for (int c = 0; c < 9; ++c)
        #pragma unroll
        for (int kb = 0; kb < 4; ++kb)
            acc[c] = __builtin_amdgcn_mfma_f32_16x16x32_bf16(a[kb], fragB[(c * 4 + kb) * 64 + l], acc[c], 0, 0, 0);
    __syncthreads();

    int rowd = w * 16 + (l >> 4) * 4;
    int cold = l & 15;
    #pragma unroll
    for (int c = 0; c < 9; ++c)
        #pragma unroll
        for (int r = 0; r < 4; ++r)
            Yl[(rowd + r) * 145 + c * 16 + cold] = acc[c][r];
    __syncthreads();

    for (int c2 = tid; c2 < 4160; c2 += 256) {
        int nn = (c2 >= 2080) ? 1 : 0;
        int r  = c2 - nn * 2080;
        int k  = r >> 5, j = r & 31;
        int rl = nn * 32 + j;
        float sc = (k == 0 || k == 64) ? (1.f / 128.f) : (2.f / 128.f);
        wfs[(size_t)(o0 + nn) * 2080 + r] =
            make_float2(Yl[rl * 145 + k] * sc, -Yl[rl * 145 + 65 + k] * sc);
    }
}

// ---------------------------------------------------------------------------
// einsum (unchanged from round 1, verified): Y[n][o][k] = sum_j X*wfs
__global__ __launch_bounds__(256) void k_einsum(const float2* __restrict__ X,
                                                const float2* __restrict__ wfs,
                                                float2* __restrict__ Y) {
    __shared__ float2 Xs[2][NF * 32];
    int tid = threadIdx.x;
    int n0  = blockIdx.x * 2;
    for (int f = tid; f < 2 * NF * 32; f += 256) {
        int nn = (f >= NF * 32) ? 1 : 0;
        int r  = f - nn * NF * 32;
        int k  = r >> 5, j = r & 31;
        Xs[nn][(k << 5) + ((j + k) & 31)] = X[(size_t)(n0 + nn) * NF * 32 + r];
    }
    __syncthreads();
    for (int oki = tid; oki < 32 * NF; oki += 256) {
        int o = oki / NF;
        int k = oki - o * NF;
        const float2* wrow = wfs + (size_t)oki * 32;
        const float2* x0 = &Xs[0][k << 5];
        const float2* x1 = &Xs[1][k << 5];
        float r0 = 0.f, i0 = 0.f, r1 = 0.f, i1 = 0.f;
        int jr = k & 31;
        #pragma unroll 8
        for (int j = 0; j < 32; ++j) {
            float2 wv = wrow[j];
            float2 a  = x0[jr];
            float2 b  = x1[jr];
            r0 = fmaf(a.x, wv.x, r0); r0 = fmaf(-a.y, wv.y, r0);
            i0 = fmaf(a.x, wv.y, i0); i0 = fmaf( a.y, wv.x, i0);
            r1 = fmaf(b.x, wv.x, r1); r1 = fmaf(-b.y, wv.y, r1);
            i1 = fmaf(b.x, wv.y, i1); i1 = fmaf( b.y, wv.x, i1);
            jr = (jr + 1) & 31;
        }
        Y[(size_t)(n0 + 0) * 32 * NF + oki] = make_float2(r0, i0);
        Y[(size_t)(n0 + 1) * 32 * NF + oki] = make_float2(r1, i1);
    }
}

// ---------------------------------------------------------------------------
// Stage C: out[row][t] = sum_kr Yr2[row][kr] * Ci[kr][t], rows=(n,o), K=160 pad
__global__ __launch_bounds__(256) void k_idft_mfma(const float2* __restrict__ Y,
                                                   const bf16x8* __restrict__ fragCi,
                                                   float* __restrict__ out) {
    __shared__ char smem[20480];            // ys[64][160] bf16, swizzled
    int tid = threadIdx.x;
    int row0 = blockIdx.x * 64;

    for (int i = tid; i < 1920; i += 256) { // zero pad cols 130..159
        int rl = i / 30, cp = 130 + i % 30;
        int byte = (rl * 320 + cp * 2) ^ ((rl & 7) << 4);
        *(unsigned short*)(smem + byte) = 0;
    }
    for (int c2 = tid; c2 < 4160; c2 += 256) {
        int rl = c2 / 65, kr = c2 % 65;
        float2 y = Y[(size_t)(row0 + rl) * 65 + kr];
        int b1 = (rl * 320 + kr * 2) ^ ((rl & 7) << 4);
        int b2 = (rl * 320 + (65 + kr) * 2) ^ ((rl & 7) << 4);
        *(unsigned short*)(smem + b1) = f2bf(y.x);
        *(unsigned short*)(smem + b2) = f2bf(y.y);
    }
    __syncthreads();

    int l = tid & 63, w = tid >> 6;
    int rl_a = w * 16 + (l & 15);
    int coff = (l >> 4) * 16;
    bf16x8 a[5];
    #pragma unroll
    for (int kb = 0; kb < 5; ++kb) {
        int byte = (rl_a * 320 + kb * 64 + coff) ^ ((rl_a & 7) << 4);
        a[kb] = *(const bf16x8*)(smem + byte);
    }
    f32x4 acc[8];
    #pragma unroll
    for (int c = 0; c < 8; ++c) acc[c] = (f32x4)0.f;
    #pragma unroll
    for (int c = 0; c < 8; ++c)
        #pragma unroll
        for (int kb = 0; kb < 5; ++kb)
            acc[c] = __builtin_amdgcn_mfma_f32_16x16x32_bf16(a[kb], fragCi[(c * 5 + kb) * 64 + l], acc[c], 0, 0, 0);

    int rowd = row0 + w * 16 + (l >> 4) * 4;
    int cold = l & 15;
    #pragma unroll
    for (int c = 0; c < 8; ++c)
        #pragma unroll
        for (int r = 0; r < 4; ++r)
            out[(size_t)(rowd + r) * 128 + c * 16 + cold] = acc[c][r];
}

// ---------------------------------------------------------------------------
extern "C" void kernel_launch(void* const* d_in, const int* in_sizes, int n_in,
                              void* d_out, int out_size, void* d_ws, size_t ws_size,
                              hipStream_t stream) {
    const float* x = (const float*)d_in[0];
    const float* W = (const float*)d_in[1];
    const float* D = (const float*)d_in[2];
    float* out = (float*)d_out;
    float* ws  = (float*)d_ws;

    // ws layout (float offsets):
    float2* wfs = (float2*)ws;                              // 133120 floats
    float2* X   = (float2*)(ws + 133120);                   // 4259840 floats
    float2* Y   = (float2*)(ws + 4392960);                  // 4259840 floats
    unsigned short* fragB  = (unsigned short*)(ws + 8652800);  // 18432 bf16
    unsigned short* fragCi = (unsigned short*)(ws + 8662016);  // 20480 bf16
    // total 34,689,024 bytes

    k_init_frag<<<80, 256, 0, stream>>>(fragB, fragCi);
    k_wfs_mfma <<<16, 256, 0, stream>>>(W, (const bf16x8*)fragB, wfs);
    k_fdft_mfma<<<512, 256, 0, stream>>>(x, D, (const bf16x8*)fragB, X);
    k_einsum   <<<512, 256, 0, stream>>>(X, wfs, Y);
    k_idft_mfma<<<512, 256, 0, stream>>>(Y, (const bf16x8*)fragCi, out);
}

// Round 3
// 47.579 us; speedup vs baseline: 4.0107x; 1.6442x over previous
//
#include <hip/hip_runtime.h>
#include <hip/hip_bf16.h>

#define BATCH 1024
#define NF    65
#define TWOPI_OVER_B 0.049087385212340517f  // 2*pi/128

typedef __attribute__((ext_vector_type(8))) short bf16x8;
typedef __attribute__((ext_vector_type(4))) float f32x4;

static __device__ __forceinline__ unsigned short f2bf(float f) {
    __hip_bfloat16 h = __float2bfloat16(f);
    return *reinterpret_cast<unsigned short*>(&h);
}
static __device__ __forceinline__ unsigned long long pack4(float a, float b, float c, float d) {
    return (unsigned long long)f2bf(a) | ((unsigned long long)f2bf(b) << 16)
         | ((unsigned long long)f2bf(c) << 32) | ((unsigned long long)f2bf(d) << 48);
}

// ---------------------------------------------------------------------------
// DFT matrices in MFMA B-fragment order (bf16).
// fragB : stage-A/W B-operand, B[t][kr]: kr<65 cos, kr in [65,130) -sin
// fragCi: stage-C B-operand, Ci[kr][t] (K=160 padded, N=128)
__global__ __launch_bounds__(256) void k_init_frag(unsigned short* __restrict__ fragB,
                                                   unsigned short* __restrict__ fragCi) {
    int i = blockIdx.x * 256 + threadIdx.x;
    if (i < 18432) {                       // fragB: ((c*4+kb)*64 + l)*8 + e
        int e = i & 7, l = (i >> 3) & 63, kb = (i >> 9) & 3, c = i >> 11;
        int kr = c * 16 + (l & 15);
        int t  = kb * 32 + (l >> 4) * 8 + e;
        float v = 0.f;
        if (kr < 65)       v =  cosf(TWOPI_OVER_B * (float)((kr * t) & 127));
        else if (kr < 130) v = -sinf(TWOPI_OVER_B * (float)(((kr - 65) * t) & 127));
        fragB[i] = f2bf(v);
    }
    if (i < 20480) {                       // fragCi: ((c*5+kb)*64 + l)*8 + e
        int e = i & 7, l = (i >> 3) & 63;
        int ckb = i >> 9; int kb = ckb % 5, c = ckb / 5;
        int kr = kb * 32 + (l >> 4) * 8 + e;
        int t  = c * 16 + (l & 15);
        float v = 0.f;
        if (kr < 65)       v =  cosf(TWOPI_OVER_B * (float)((kr * t) & 127));
        else if (kr < 130) v = -sinf(TWOPI_OVER_B * (float)(((kr - 65) * t) & 127));
        fragCi[i] = f2bf(v);
    }
}

#define SMEM_A_BYTES 37120   // max(xs 16384, Yl 64*145*4=37120)

// ---------------------------------------------------------------------------
// Stage A: Xb[k][n][j2] (bf16, [65][1024][64]) = DFT of x*D blocks.
// j2<32: Re_j, j2>=32: Im_{j2-32}
__global__ __launch_bounds__(256) void k_fdft_mfma(const float* __restrict__ x,
                                                   const float* __restrict__ D,
                                                   const bf16x8* __restrict__ fragB,
                                                   unsigned short* __restrict__ Xb) {
    __shared__ char smem[SMEM_A_BYTES];
    unsigned long long* xs8 = (unsigned long long*)smem;
    float* Yl = (float*)smem;
    int tid = threadIdx.x;
    int n0 = blockIdx.x * 2;

    #pragma unroll
    for (int it = 0; it < 8; ++it) {       // 2048 float4 = 2 rows of x
        int f  = tid + it * 256;
        int nn = f >> 10;
        int f4 = f & 1023;
        float4 xa = ((const float4*)(x + (size_t)(n0 + nn) * 4096))[f4];
        float4 da = ((const float4*)D)[f4];
        int rl = nn * 32 + (f4 >> 5);
        int t0 = (f4 & 31) * 4;
        unsigned long long pk = pack4(xa.x * da.x, xa.y * da.y, xa.z * da.z, xa.w * da.w);
        int byte = (rl * 256 + t0 * 2) ^ ((rl & 7) << 4);
        xs8[byte >> 3] = pk;
    }
    __syncthreads();

    int l = tid & 63, w = tid >> 6;
    int rl_a = w * 16 + (l & 15);
    int coff = (l >> 4) * 16;
    bf16x8 a[4];
    #pragma unroll
    for (int kb = 0; kb < 4; ++kb) {
        int byte = (rl_a * 256 + kb * 64 + coff) ^ ((rl_a & 7) << 4);
        a[kb] = *(const bf16x8*)(smem + byte);
    }
    f32x4 acc[9];
    #pragma unroll
    for (int c = 0; c < 9; ++c) acc[c] = (f32x4)0.f;
    #pragma unroll
    for (int c = 0; c < 9; ++c)
        #pragma unroll
        for (int kb = 0; kb < 4; ++kb)
            acc[c] = __builtin_amdgcn_mfma_f32_16x16x32_bf16(a[kb], fragB[(c * 4 + kb) * 64 + l], acc[c], 0, 0, 0);
    __syncthreads();                        // xs dead; reuse as Yl

    int rowd = w * 16 + (l >> 4) * 4;
    int cold = l & 15;
    #pragma unroll
    for (int c = 0; c < 9; ++c)
        #pragma unroll
        for (int r = 0; r < 4; ++r)
            Yl[(rowd + r) * 145 + c * 16 + cold] = acc[c][r];
    __syncthreads();

    for (int c2 = tid; c2 < 2080; c2 += 256) {
        int k = c2 >> 5, sub = c2 & 31, nn = sub >> 4, t = sub & 15;
        int j0 = t * 4;
        int col = (j0 < 32) ? k : 65 + k;
        int rlb = nn * 32 + (j0 & 31);
        unsigned long long pk = pack4(Yl[(rlb + 0) * 145 + col], Yl[(rlb + 1) * 145 + col],
                                      Yl[(rlb + 2) * 145 + col], Yl[(rlb + 3) * 145 + col]);
        *(unsigned long long*)(Xb + ((size_t)k * 1024 + n0 + nn) * 64 + j0) = pk;
    }
}

// ---------------------------------------------------------------------------
// W spectrum -> real-expanded per-k B matrix, transposed:
// BmatT[k][o2][j2] (bf16, [65][64][64]), row-contiguous for direct B-frags.
//   o2=o,   j2=j   :  wr   = sc*Yl[oj][k]
//   o2=o,   j2=32+j:  -wi  = sc*Yl[oj][65+k]
//   o2=32+o,j2=j   :  wi   = -sc*Yl[oj][65+k]
//   o2=32+o,j2=32+j:  wr   = sc*Yl[oj][k]
__global__ __launch_bounds__(256) void k_wfs_mfma(const float* __restrict__ W,
                                                  const bf16x8* __restrict__ fragB,
                                                  unsigned short* __restrict__ BmatT) {
    __shared__ char smem[SMEM_A_BYTES];
    unsigned long long* xs8 = (unsigned long long*)smem;
    float* Yl = (float*)smem;
    int tid = threadIdx.x;
    int o0 = blockIdx.x * 2;

    #pragma unroll
    for (int it = 0; it < 8; ++it) {        // 64 rows x 128 = 2048 float4
        int f  = tid + it * 256;
        float4 wa = ((const float4*)W)[(size_t)blockIdx.x * 2048 + f];
        int rl = f >> 5;
        int t0 = (f & 31) * 4;
        unsigned long long pk = pack4(wa.x, wa.y, wa.z, wa.w);
        int byte = (rl * 256 + t0 * 2) ^ ((rl & 7) << 4);
        xs8[byte >> 3] = pk;
    }
    __syncthreads();

    int l = tid & 63, w = tid >> 6;
    int rl_a = w * 16 + (l & 15);
    int coff = (l >> 4) * 16;
    bf16x8 a[4];
    #pragma unroll
    for (int kb = 0; kb < 4; ++kb) {
        int byte = (rl_a * 256 + kb * 64 + coff) ^ ((rl_a & 7) << 4);
        a[kb] = *(const bf16x8*)(smem + byte);
    }
    f32x4 acc[9];
    #pragma unroll
    for (int c = 0; c < 9; ++c) acc[c] = (f32x4)0.f;
    #pragma unroll
    for (int c = 0; c < 9; ++c)
        #pragma unroll
        for (int kb = 0; kb < 4; ++kb)
            acc[c] = __builtin_amdgcn_mfma_f32_16x16x32_bf16(a[kb], fragB[(c * 4 + kb) * 64 + l], acc[c], 0, 0, 0);
    __syncthreads();

    int rowd = w * 16 + (l >> 4) * 4;
    int cold = l & 15;
    #pragma unroll
    for (int c = 0; c < 9; ++c)
        #pragma unroll
        for (int r = 0; r < 4; ++r)
            Yl[(rowd + r) * 145 + c * 16 + cold] = acc[c][r];
    __syncthreads();

    for (int c2 = tid; c2 < 4160; c2 += 256) {
        int k = c2 >> 6, sub = c2 & 63;
        int oo = sub >> 5, h = (sub >> 4) & 1, t = sub & 15;
        int j0 = t * 4;
        float sc = (k == 0 || k == 64) ? (1.f / 128.f) : (2.f / 128.f);
        int col; float sgn;
        if (j0 < 32) { col = h ? 65 + k : k;  sgn = h ? -sc : sc; }
        else         { col = h ? k : 65 + k;  sgn = sc; }
        int rlb = oo * 32 + (j0 & 31);
        unsigned long long pk = pack4(sgn * Yl[(rlb + 0) * 145 + col], sgn * Yl[(rlb + 1) * 145 + col],
                                      sgn * Yl[(rlb + 2) * 145 + col], sgn * Yl[(rlb + 3) * 145 + col]);
        int o2 = h * 32 + o0 + oo;
        *(unsigned long long*)(BmatT + ((size_t)k * 64 + o2) * 64 + j0) = pk;
    }
}

// ---------------------------------------------------------------------------
// Stage B: per-k real GEMM [1024x64]x[64x64] -> Y2[k][n][o2] bf16.
// grid = 65 k * 8 m-tiles; block 256 = 4 waves; wave: 32 rows x 64 cols.
__global__ __launch_bounds__(256) void k_einsum_mfma(const unsigned short* __restrict__ Xb,
                                                     const unsigned short* __restrict__ BmatT,
                                                     unsigned short* __restrict__ Y2) {
    __shared__ char lds[16384];
    int tid = threadIdx.x, l = tid & 63, w = tid >> 6;
    int k = blockIdx.x >> 3, mt = blockIdx.x & 7;
    int m0 = mt * 128 + w * 32;
    int lr = l & 15, lq = l >> 4;

    bf16x8 a[2][2], b[4][2];
    #pragma unroll
    for (int rf = 0; rf < 2; ++rf)
        #pragma unroll
        for (int kb = 0; kb < 2; ++kb)
            a[rf][kb] = *(const bf16x8*)(Xb + ((size_t)k * 1024 + m0 + rf * 16 + lr) * 64 + kb * 32 + lq * 8);
    #pragma unroll
    for (int cf = 0; cf < 4; ++cf)
        #pragma unroll
        for (int kb = 0; kb < 2; ++kb)
            b[cf][kb] = *(const bf16x8*)(BmatT + ((size_t)k * 64 + cf * 16 + lr) * 64 + kb * 32 + lq * 8);

    f32x4 acc[2][4];
    #pragma unroll
    for (int rf = 0; rf < 2; ++rf)
        #pragma unroll
        for (int cf = 0; cf < 4; ++cf) acc[rf][cf] = (f32x4)0.f;
    #pragma unroll
    for (int rf = 0; rf < 2; ++rf)
        #pragma unroll
        for (int cf = 0; cf < 4; ++cf) {
            acc[rf][cf] = __builtin_amdgcn_mfma_f32_16x16x32_bf16(a[rf][0], b[cf][0], acc[rf][cf], 0, 0, 0);
            acc[rf][cf] = __builtin_amdgcn_mfma_f32_16x16x32_bf16(a[rf][1], b[cf][1], acc[rf][cf], 0, 0, 0);
        }

    // per-wave repack to bf16 rows, then coalesced stores
    #pragma unroll
    for (int rf = 0; rf < 2; ++rf)
        #pragma unroll
        for (int cf = 0; cf < 4; ++cf)
            #pragma unroll
            for (int rr = 0; rr < 4; ++rr) {
                int row = rf * 16 + lq * 4 + rr;
                int col = cf * 16 + lr;
                int byte = w * 4096 + ((row * 128 + col * 2) ^ ((row & 7) << 4));
                *(unsigned short*)(lds + byte) = f2bf(acc[rf][cf][rr]);
            }
    __syncthreads();
    #pragma unroll
    for (int i = 0; i < 4; ++i) {
        int row = i * 8 + (l >> 3);
        int byte = w * 4096 + ((row * 128 + (l & 7) * 16) ^ ((row & 7) << 4));
        bf16x8 v = *(const bf16x8*)(lds + byte);
        *(bf16x8*)(Y2 + ((size_t)k * 1024 + m0 + row) * 64 + (l & 7) * 8) = v;
    }
}

// ---------------------------------------------------------------------------
// Stage C: out[(n,o) row][t] = sum_kr ys[row][kr] * Ci[kr][t], K=160 pad.
__global__ __launch_bounds__(256) void k_idft_mfma(const unsigned short* __restrict__ Y2,
                                                   const bf16x8* __restrict__ fragCi,
                                                   float* __restrict__ out) {
    __shared__ char smem[20480];            // ys[64][160] bf16, swizzled
    int tid = threadIdx.x;
    int row0 = blockIdx.x * 64;
    int n0 = blockIdx.x * 2;

    for (int i = tid; i < 1920; i += 256) { // zero pad cols 130..159
        int rl = i / 30, cp = 130 + i % 30;
        int byte = (rl * 320 + cp * 2) ^ ((rl & 7) << 4);
        *(unsigned short*)(smem + byte) = 0;
    }
    for (int c2 = tid; c2 < 2080; c2 += 256) {
        int k = c2 >> 5, sub = c2 & 31, nn = sub >> 4, t = sub & 15;
        unsigned long long v = *(const unsigned long long*)(Y2 + ((size_t)k * 1024 + n0 + nn) * 64 + t * 4);
        int o2_0 = t * 4;
        int col = (o2_0 < 32) ? k : 65 + k;
        int r0 = nn * 32 + (o2_0 & 31);
        #pragma unroll
        for (int i = 0; i < 4; ++i) {
            int rl = r0 + i;
            int byte = (rl * 320 + col * 2) ^ ((rl & 7) << 4);
            *(unsigned short*)(smem + byte) = (unsigned short)(v >> (16 * i));
        }
    }
    __syncthreads();

    int l = tid & 63, w = tid >> 6;
    int rl_a = w * 16 + (l & 15);
    int coff = (l >> 4) * 16;
    bf16x8 a[5];
    #pragma unroll
    for (int kb = 0; kb < 5; ++kb) {
        int byte = (rl_a * 320 + kb * 64 + coff) ^ ((rl_a & 7) << 4);
        a[kb] = *(const bf16x8*)(smem + byte);
    }
    f32x4 acc[8];
    #pragma unroll
    for (int c = 0; c < 8; ++c) acc[c] = (f32x4)0.f;
    #pragma unroll
    for (int c = 0; c < 8; ++c)
        #pragma unroll
        for (int kb = 0; kb < 5; ++kb)
            acc[c] = __builtin_amdgcn_mfma_f32_16x16x32_bf16(a[kb], fragCi[(c * 5 + kb) * 64 + l], acc[c], 0, 0, 0);

    int rowd = row0 + w * 16 + (l >> 4) * 4;
    int cold = l & 15;
    #pragma unroll
    for (int c = 0; c < 8; ++c)
        #pragma unroll
        for (int r = 0; r < 4; ++r)
            out[(size_t)(rowd + r) * 128 + c * 16 + cold] = acc[c][r];
}

// ---------------------------------------------------------------------------
extern "C" void kernel_launch(void* const* d_in, const int* in_sizes, int n_in,
                              void* d_out, int out_size, void* d_ws, size_t ws_size,
                              hipStream_t stream) {
    const float* x = (const float*)d_in[0];
    const float* W = (const float*)d_in[1];
    const float* D = (const float*)d_in[2];
    float* out = (float*)d_out;
    float* ws  = (float*)d_ws;

    // ws layout (float offsets), total ~17.7 MB:
    unsigned short* BmatT  = (unsigned short*)ws;                   // 266240 bf16
    unsigned short* Xb     = (unsigned short*)(ws + 133120);        // 4259840 bf16
    unsigned short* Y2     = (unsigned short*)(ws + 2263040);       // 4259840 bf16
    unsigned short* fragB  = (unsigned short*)(ws + 4392960);       // 18432 bf16
    unsigned short* fragCi = (unsigned short*)(ws + 4402176);       // 20480 bf16

    k_init_frag  <<<80, 256, 0, stream>>>(fragB, fragCi);
    k_wfs_mfma   <<<16, 256, 0, stream>>>(W, (const bf16x8*)fragB, BmatT);
    k_fdft_mfma  <<<512, 256, 0, stream>>>(x, D, (const bf16x8*)fragB, Xb);
    k_einsum_mfma<<<520, 256, 0, stream>>>(Xb, BmatT, Y2);
    k_idft_mfma  <<<512, 256, 0, stream>>>(Y2, (const bf16x8*)fragCi, out);
}